// Round 9
// baseline (148.296 us; speedup 1.0000x reference)
//
#include <hip/hip_runtime.h>
#include <hip/hip_bf16.h>
#include <stdint.h>

// ConvMoE: B=32, C=384, H=W=28, E=4, HID=384, K=2. N tokens = 25088.
// GEMM1: [25088,384] x [1536,384]^T -> hdnS (coef*relu fused, bf16)
// GEMM2: [25088,1536] x [384,1536]^T -> out (fp32) + sum_e coef*b2
// Both: BM=256 x BN=128, BK=32, 4 waves with 128x64 wave-tiles (halves LDS
// bytes/FLOP vs 64x64), 3 LDS buffers (72KB, 2 blk/CU), depth-2 prefetch.
#define B_DIM 32
#define C_DIM 384
#define HW_DIM 784
#define E_DIM 4
#define HID_DIM 384
#define NTOK (B_DIM * HW_DIM)   // 25088
#define NH (E_DIM * HID_DIM)    // 1536

using short8 = __attribute__((ext_vector_type(8))) short;
using f32x4  = __attribute__((ext_vector_type(4))) float;
typedef unsigned short ushort_t;

__device__ __forceinline__ ushort_t f2bf(float f) {
  __hip_bfloat16 h = __float2bfloat16(f);
  return __builtin_bit_cast(ushort_t, h);
}

__device__ __forceinline__ void gload_lds16(const void* g, void* l) {
  __builtin_amdgcn_global_load_lds(
      (const __attribute__((address_space(1))) unsigned int*)g,
      (__attribute__((address_space(3))) unsigned int*)l, 16, 0, 0);
}

// ---------------- kernel 1: weight convert (+ zero present mask) -------------
__global__ __launch_bounds__(256) void prep_kernel(
    const float* __restrict__ w1, const float* __restrict__ w2,
    ushort_t* __restrict__ W1b, ushort_t* __restrict__ W2b,
    unsigned int* __restrict__ present) {
  int i = blockIdx.x * 256 + threadIdx.x;
  if (i == 0) *present = 0u;
  if (i < NH * C_DIM) {
    W1b[i] = f2bf(w1[i]);                       // [e*HID+d][c]
    int o = i / NH;
    int r = i - o * NH;
    int e = r / HID_DIM;
    int k = r - e * HID_DIM;
    W2b[i] = f2bf(w2[((size_t)e * C_DIM + o) * HID_DIM + k]);  // [o][e*384+k]
  }
}

// ---------------- kernel 2: gate + softmax + top2 + x -> bf16 [N][C] ---------
__global__ __launch_bounds__(256) void gate_kernel(
    const float* __restrict__ x, const float* __restrict__ gw,
    const float* __restrict__ gb, ushort_t* __restrict__ xb,
    float* __restrict__ topw, unsigned int* __restrict__ present) {
  __shared__ __align__(16) ushort_t lxs[64][392];
  __shared__ float pscore[4][64][4];
  __shared__ unsigned int pmask;
  const int b = blockIdx.x;
  const int p0 = blockIdx.y * 64;
  const int cnt = min(64, HW_DIM - p0);
  const int tid = threadIdx.x;
  const int cg = tid >> 6, tl = tid & 63;
  if (tid == 0) pmask = 0u;
  float a0 = 0.f, a1 = 0.f, a2 = 0.f, a3 = 0.f;
  const bool valid = tl < cnt;
  if (valid) {
    const float* xp = x + (size_t)b * C_DIM * HW_DIM + p0 + tl;
    for (int c = cg; c < C_DIM; c += 4) {
      const float v = xp[(size_t)c * HW_DIM];
      lxs[tl][c] = f2bf(v);
      const float4 g = *(const float4*)&gw[c * 4];
      a0 += v * g.x; a1 += v * g.y; a2 += v * g.z; a3 += v * g.w;
    }
  }
  pscore[cg][tl][0] = a0; pscore[cg][tl][1] = a1;
  pscore[cg][tl][2] = a2; pscore[cg][tl][3] = a3;
  __syncthreads();
  if (cg == 0 && valid) {
    float z[4];
#pragma unroll
    for (int e = 0; e < 4; e++)
      z[e] = pscore[0][tl][e] + pscore[1][tl][e] + pscore[2][tl][e] +
             pscore[3][tl][e] + gb[e];
    const float mx = fmaxf(fmaxf(z[0], z[1]), fmaxf(z[2], z[3]));
    float s[4]; float sum = 0.f;
#pragma unroll
    for (int e = 0; e < 4; e++) { s[e] = __expf(z[e] - mx); sum += s[e]; }
    const float inv = 1.f / sum;
#pragma unroll
    for (int e = 0; e < 4; e++) s[e] *= inv;
    int e0 = 0; float v0 = s[0];
#pragma unroll
    for (int e = 1; e < 4; e++) if (s[e] > v0) { v0 = s[e]; e0 = e; }
    int e1 = -1; float v1 = -1.f;
#pragma unroll
    for (int e = 0; e < 4; e++) if (e != e0 && s[e] > v1) { v1 = s[e]; e1 = e; }
    const float r = __expf(v1 - v0);
    const float w0 = 1.f / (1.f + r);
    const int m = b * HW_DIM + p0 + tl;
    topw[m * 2] = w0;
    topw[m * 2 + 1] = 1.f - w0;
    atomicOr(&pmask, (1u << e0) | (1u << (4 + e1)));
  }
  __syncthreads();
  if (tid == 0) atomicOr(present, pmask);
  const int nchunk = cnt * 48;
  for (int ci = tid; ci < nchunk; ci += 256) {
    const int row = ci / 48, c8 = ci - row * 48;
    short8 v = *(const short8*)&lxs[row][c8 * 8];
    *(short8*)&xb[(size_t)(b * HW_DIM + p0 + row) * C_DIM + c8 * 8] = v;
  }
}

// ---- 256x128, BK=32, 4 waves (128x64 wave-tile), 3-buffer 72KB, 2 blk/CU ----
// LDS bytes/FLOP = 0.035 (vs 0.047 at 64x64 wave-tiles) — LDS-BW relief.
// T1 XCD-swizzle, T2 both-sides XOR ((row>>1)&3)<<4 (0 conflicts, r8), T5.
// C[M,128] = A[M,K] * Bw[cols,K]^T ; EPI 0: hdnS epilogue, 1: out epilogue
template <int KDIM, int EPI>
__global__ __launch_bounds__(256, 2) void gemm_v9(
    const ushort_t* __restrict__ A, const ushort_t* __restrict__ Bw,
    const float* __restrict__ bias, const float* __restrict__ topw,
    const unsigned int* __restrict__ presentp,
    ushort_t* __restrict__ hOut, float* __restrict__ outp) {
  constexpr int BM = 256, BN = 128, BK = 32;
  constexpr int KT = KDIM / BK;                    // 12 or 48
  constexpr int NTN = (EPI == 0 ? NH / BN : C_DIM / BN);  // 12 or 3
  constexpr int ASZ = BM * BK;                     // 8192 ushorts = 16 KB
  constexpr int BSZ = BN * BK;                     // 4096 ushorts = 8 KB
  __shared__ ushort_t smem[3 * ASZ + 3 * BSZ];     // 72 KB -> 2 blk/CU

  // T1: bijective XCD swizzle (m204)
  const int nwg = NTN * (NTOK / BM);
  const int orig = blockIdx.x;
  const int xcd = orig & 7;
  const int qq = nwg >> 3, rr = nwg & 7;
  const int wg = (xcd < rr ? xcd * (qq + 1) : rr * (qq + 1) + (xcd - rr) * qq)
               + (orig >> 3);
  const int mt = wg / NTN, nt = wg % NTN;
  const int m0 = mt * BM, n0 = nt * BN;

  const int tid = threadIdx.x;
  const int lane = tid & 63;
  const int wid = tid >> 6;
  const int wm = wid >> 1, wn = wid & 1;           // wave tile 128x64
  const int lanel = lane & 15, laneq = lane >> 4;

  // T2 swizzle for 64B rows: key ((row>>1)&3)<<4 (2 rows/slot = free, m136).
  // Linear LDS dest for global_load_lds, pre-swizzled GLOBAL source.
  auto stage = [&](int t) {
    const int buf = t % 3;
    ushort_t* dstA = smem + buf * ASZ;
    ushort_t* dstB = smem + 3 * ASZ + buf * BSZ;
    const int kb = t * BK;
#pragma unroll
    for (int li = 0; li < 4; ++li) {               // A: 16 KB = 1024 x 16B
      const int P = (li * 256 + tid) * 16;
      const int row = P >> 6;
      const int cb = (P & 63) ^ (((row >> 1) & 3) << 4);
      gload_lds16(&A[(size_t)(m0 + row) * KDIM + kb + (cb >> 1)],
                  (char*)dstA + P);
    }
#pragma unroll
    for (int li = 0; li < 2; ++li) {               // B: 8 KB = 512 x 16B
      const int P = (li * 256 + tid) * 16;
      const int row = P >> 6;
      const int cb = (P & 63) ^ (((row >> 1) & 3) << 4);
      gload_lds16(&Bw[(size_t)(n0 + row) * KDIM + kb + (cb >> 1)],
                  (char*)dstB + P);
    }
  };

  f32x4 acc[8][4] = {};
  // per-lane swizzled byte-col (row = base + i*16 + lanel, base%64==0)
  const int cbr = (laneq * 16) ^ (((lanel >> 1) & 3) << 4);

  stage(0);
  stage(1);
  for (int t = 0; t < KT; ++t) {
    if (t + 2 < KT) stage(t + 2);        // buffer freed at t-1's end barrier
    // counted vmcnt: wait tile t's 6 loads; keep up to 12 (2 tiles) in flight
    const int ahead = min(2, KT - 1 - t);
    if (ahead == 2)      asm volatile("s_waitcnt vmcnt(12)" ::: "memory");
    else if (ahead == 1) asm volatile("s_waitcnt vmcnt(6)" ::: "memory");
    else                 asm volatile("s_waitcnt vmcnt(0)" ::: "memory");
    __builtin_amdgcn_sched_barrier(0);
    __builtin_amdgcn_s_barrier();
    __builtin_amdgcn_sched_barrier(0);
    const int buf = t % 3;
    const char* Ab =
        (const char*)(smem + buf * ASZ) + (wm * 128 + lanel) * 64;
    const char* Bb =
        (const char*)(smem + 3 * ASZ + buf * BSZ) + (wn * 64 + lanel) * 64;
    short8 av[8], bv[4];                 // each frag read ONCE per K-step
#pragma unroll
    for (int i = 0; i < 8; ++i) av[i] = *(const short8*)(Ab + i * 1024 + cbr);
#pragma unroll
    for (int j = 0; j < 4; ++j) bv[j] = *(const short8*)(Bb + j * 1024 + cbr);
    __builtin_amdgcn_s_setprio(1);                 // T5
#pragma unroll
    for (int i = 0; i < 8; ++i)
#pragma unroll
      for (int j = 0; j < 4; ++j)
        acc[i][j] = __builtin_amdgcn_mfma_f32_16x16x32_bf16(
            av[i], bv[j], acc[i][j], 0, 0, 0);
    __builtin_amdgcn_s_setprio(0);
    __builtin_amdgcn_sched_barrier(0);
    __builtin_amdgcn_s_barrier();        // all waves done reading buf
    __builtin_amdgcn_sched_barrier(0);
  }

  const unsigned int pm = *presentp;
  if constexpr (EPI == 0) {
    // coef*relu + bf16; two 128-row halves via 32KB LDS transpose
    __syncthreads();
    ushort_t* tr = smem;                           // 128x128 bf16 = 32 KB
    const int e = n0 / HID_DIM;                    // 128-col tile: one expert
    const float P0 = (float)((pm >> e) & 1u);
    const float P1 = (float)((pm >> (4 + e)) & 1u);
#pragma unroll
    for (int s = 0; s < 2; ++s) {
      if (wm == s) {
#pragma unroll
        for (int mi = 0; mi < 8; ++mi) {
          const int rloc = mi * 16 + laneq * 4;
          const int mg = m0 + s * 128 + rloc;
          const float4 t0 = *(const float4*)&topw[mg * 2];
          const float4 t1 = *(const float4*)&topw[mg * 2 + 4];
          const float cj[4] = {P0 * t0.x + P1 * t0.y, P0 * t0.z + P1 * t0.w,
                               P0 * t1.x + P1 * t1.y, P0 * t1.z + P1 * t1.w};
#pragma unroll
          for (int ni = 0; ni < 4; ++ni) {
            const int cl = wn * 64 + ni * 16 + lanel;
            const float bvv = bias[n0 + cl];
#pragma unroll
            for (int j = 0; j < 4; ++j) {
              float v = fmaxf(acc[mi][ni][j] + bvv, 0.f);
              tr[(rloc + j) * 128 + cl] = f2bf(cj[j] * v);
            }
          }
        }
      }
      __syncthreads();
#pragma unroll
      for (int it = 0; it < 8; ++it) {             // 128x128 = 2048 x short8
        const int c = it * 256 + tid;
        const int row = c >> 4, cr = c & 15;
        *(short8*)&hOut[(size_t)(m0 + s * 128 + row) * NH + n0 + cr * 8] =
            *(const short8*)&tr[row * 128 + cr * 8];
      }
      __syncthreads();
    }
  } else {
    float B0[4], B1[4];
#pragma unroll
    for (int ni = 0; ni < 4; ++ni) {
      const int o = n0 + wn * 64 + ni * 16 + lanel;
      float s0 = 0.f, s1 = 0.f;
#pragma unroll
      for (int e2 = 0; e2 < 4; ++e2) {
        const float bb = bias[e2 * C_DIM + o];
        s0 += (float)((pm >> e2) & 1u) * bb;
        s1 += (float)((pm >> (4 + e2)) & 1u) * bb;
      }
      B0[ni] = s0; B1[ni] = s1;
    }
#pragma unroll
    for (int mi = 0; mi < 8; ++mi) {
      const int mg = m0 + wm * 128 + mi * 16 + laneq * 4;
      const float4 t0 = *(const float4*)&topw[mg * 2];
      const float4 t1 = *(const float4*)&topw[mg * 2 + 4];
      const int bb2 = mg / HW_DIM;
      const int p = mg - bb2 * HW_DIM;             // 4 consecutive p, same b
#pragma unroll
      for (int ni = 0; ni < 4; ++ni) {
        const int o = n0 + wn * 64 + ni * 16 + lanel;
        float4 v;
        v.x = acc[mi][ni][0] + t0.x * B0[ni] + t0.y * B1[ni];
        v.y = acc[mi][ni][1] + t0.z * B0[ni] + t0.w * B1[ni];
        v.z = acc[mi][ni][2] + t1.x * B0[ni] + t1.y * B1[ni];
        v.w = acc[mi][ni][3] + t1.z * B0[ni] + t1.w * B1[ni];
        *(float4*)&outp[((size_t)bb2 * C_DIM + o) * HW_DIM + p] = v;
      }
    }
  }
}

extern "C" void kernel_launch(void* const* d_in, const int* in_sizes, int n_in,
                              void* d_out, int out_size, void* d_ws, size_t ws_size,
                              hipStream_t stream) {
  const float* x  = (const float*)d_in[0];
  const float* gw = (const float*)d_in[1];
  const float* gb = (const float*)d_in[2];
  const float* w1 = (const float*)d_in[3];
  const float* b1 = (const float*)d_in[4];
  const float* w2 = (const float*)d_in[5];
  const float* b2 = (const float*)d_in[6];
  float* out = (float*)d_out;

  char* ws = (char*)d_ws;
  ushort_t* xb = (ushort_t*)ws;   ws += (size_t)NTOK * C_DIM * 2;
  ushort_t* hdnS = (ushort_t*)ws; ws += (size_t)NTOK * NH * 2;
  ushort_t* W1b = (ushort_t*)ws;  ws += (size_t)NH * C_DIM * 2;
  ushort_t* W2b = (ushort_t*)ws;  ws += (size_t)C_DIM * NH * 2;
  float* topw = (float*)ws;       ws += (size_t)NTOK * 2 * 4;
  unsigned int* present = (unsigned int*)ws;

  prep_kernel<<<dim3((NH * C_DIM) / 256), dim3(256), 0, stream>>>(
      w1, w2, W1b, W2b, present);
  gate_kernel<<<dim3(B_DIM, 13), dim3(256), 0, stream>>>(
      x, gw, gb, xb, topw, present);
  gemm_v9<C_DIM, 0>
      <<<dim3((NTOK / 256) * (NH / 128)), dim3(256), 0, stream>>>(
          xb, W1b, b1, topw, present, hdnS, nullptr);
  gemm_v9<NH, 1>
      <<<dim3((NTOK / 256) * (C_DIM / 128)), dim3(256), 0, stream>>>(
          hdnS, W2b, b2, topw, present, nullptr, out);
}

// Round 10
// 138.747 us; speedup vs baseline: 1.0688x; 1.0688x over previous
//
#include <hip/hip_runtime.h>
#include <hip/hip_bf16.h>
#include <stdint.h>

// ConvMoE: B=32, C=384, H=W=28, E=4, HID=384, K=2. N tokens = 25088.
// GEMM1: [25088,384] x [1536,384]^T -> hdnS (coef*relu fused, bf16)
//        m201-style 256x256 / BK=64 / 8 waves / 8-phase / counted vmcnt
// GEMM2: [25088,1536] x [384,1536]^T -> out (fp32) + sum_e coef*b2
//        r3's proven 128x128 / BK=64 / dbuf kernel
#define B_DIM 32
#define C_DIM 384
#define HW_DIM 784
#define E_DIM 4
#define HID_DIM 384
#define NTOK (B_DIM * HW_DIM)   // 25088
#define NH (E_DIM * HID_DIM)    // 1536

using short8 = __attribute__((ext_vector_type(8))) short;
using f32x4  = __attribute__((ext_vector_type(4))) float;
typedef unsigned short ushort_t;

__device__ __forceinline__ ushort_t f2bf(float f) {
  __hip_bfloat16 h = __float2bfloat16(f);
  return __builtin_bit_cast(ushort_t, h);
}

__device__ __forceinline__ void gload_lds16(const void* g, void* l) {
  __builtin_amdgcn_global_load_lds(
      (const __attribute__((address_space(1))) unsigned int*)g,
      (__attribute__((address_space(3))) unsigned int*)l, 16, 0, 0);
}

// ---------------- kernel 1: weight convert (+ zero present mask) -------------
__global__ __launch_bounds__(256) void prep_kernel(
    const float* __restrict__ w1, const float* __restrict__ w2,
    ushort_t* __restrict__ W1b, ushort_t* __restrict__ W2b,
    unsigned int* __restrict__ present) {
  int i = blockIdx.x * 256 + threadIdx.x;
  if (i == 0) *present = 0u;
  if (i < NH * C_DIM) {
    W1b[i] = f2bf(w1[i]);                       // [e*HID+d][c]
    int o = i / NH;
    int r = i - o * NH;
    int e = r / HID_DIM;
    int k = r - e * HID_DIM;
    W2b[i] = f2bf(w2[((size_t)e * C_DIM + o) * HID_DIM + k]);  // [o][e*384+k]
  }
}

// ---------------- kernel 2: gate + softmax + top2 + x -> bf16 [N][C] ---------
__global__ __launch_bounds__(256) void gate_kernel(
    const float* __restrict__ x, const float* __restrict__ gw,
    const float* __restrict__ gb, ushort_t* __restrict__ xb,
    float* __restrict__ topw, unsigned int* __restrict__ present) {
  __shared__ __align__(16) ushort_t lxs[64][392];
  __shared__ float pscore[4][64][4];
  __shared__ unsigned int pmask;
  const int b = blockIdx.x;
  const int p0 = blockIdx.y * 64;
  const int cnt = min(64, HW_DIM - p0);
  const int tid = threadIdx.x;
  const int cg = tid >> 6, tl = tid & 63;
  if (tid == 0) pmask = 0u;
  float a0 = 0.f, a1 = 0.f, a2 = 0.f, a3 = 0.f;
  const bool valid = tl < cnt;
  if (valid) {
    const float* xp = x + (size_t)b * C_DIM * HW_DIM + p0 + tl;
    for (int c = cg; c < C_DIM; c += 4) {
      const float v = xp[(size_t)c * HW_DIM];
      lxs[tl][c] = f2bf(v);
      const float4 g = *(const float4*)&gw[c * 4];
      a0 += v * g.x; a1 += v * g.y; a2 += v * g.z; a3 += v * g.w;
    }
  }
  pscore[cg][tl][0] = a0; pscore[cg][tl][1] = a1;
  pscore[cg][tl][2] = a2; pscore[cg][tl][3] = a3;
  __syncthreads();
  if (cg == 0 && valid) {
    float z[4];
#pragma unroll
    for (int e = 0; e < 4; e++)
      z[e] = pscore[0][tl][e] + pscore[1][tl][e] + pscore[2][tl][e] +
             pscore[3][tl][e] + gb[e];
    const float mx = fmaxf(fmaxf(z[0], z[1]), fmaxf(z[2], z[3]));
    float s[4]; float sum = 0.f;
#pragma unroll
    for (int e = 0; e < 4; e++) { s[e] = __expf(z[e] - mx); sum += s[e]; }
    const float inv = 1.f / sum;
#pragma unroll
    for (int e = 0; e < 4; e++) s[e] *= inv;
    int e0 = 0; float v0 = s[0];
#pragma unroll
    for (int e = 1; e < 4; e++) if (s[e] > v0) { v0 = s[e]; e0 = e; }
    int e1 = -1; float v1 = -1.f;
#pragma unroll
    for (int e = 0; e < 4; e++) if (e != e0 && s[e] > v1) { v1 = s[e]; e1 = e; }
    const float r = __expf(v1 - v0);
    const float w0 = 1.f / (1.f + r);
    const int m = b * HW_DIM + p0 + tl;
    topw[m * 2] = w0;
    topw[m * 2 + 1] = 1.f - w0;
    atomicOr(&pmask, (1u << e0) | (1u << (4 + e1)));
  }
  __syncthreads();
  if (tid == 0) atomicOr(present, pmask);
  const int nchunk = cnt * 48;
  for (int ci = tid; ci < nchunk; ci += 256) {
    const int row = ci / 48, c8 = ci - row * 48;
    short8 v = *(const short8*)&lxs[row][c8 * 8];
    *(short8*)&xb[(size_t)(b * HW_DIM + p0 + row) * C_DIM + c8 * 8] = v;
  }
}

// ---- GEMM1: 256x256, BK=64, 8 waves (2Mx4N, wave-tile 128x64), 8-phase -----
// m201 reconstruction: per K-tile 4 quadrant phases; av read once per qm
// (held 2 phases), bv0/bv1 held across the group => each half-tile LDS region
// frees one phase after its read => per-phase staging of tile t+2/t+3 into
// the live buffer. vmcnt(8) only at P0/P4. LDS 128KB: A/B x 2buf x 2half.
__global__ __launch_bounds__(512, 2) void moe_g1(
    const ushort_t* __restrict__ A, const ushort_t* __restrict__ Bw,
    const float* __restrict__ bias, const float* __restrict__ topw,
    const unsigned int* __restrict__ presentp, ushort_t* __restrict__ hOut) {
  constexpr int KT = 6;                           // 384 / 64
  __shared__ __align__(16) char smemb[131072];

  // T1: bijective XCD swizzle (m204); nt-fastest => same-mt blocks share XCD
  const int nwg = 98 * 6;
  const int orig = blockIdx.x;
  const int xcd = orig & 7;
  const int qq = nwg >> 3, rr = nwg & 7;
  const int wg = (xcd < rr ? xcd * (qq + 1) : rr * (qq + 1) + (xcd - rr) * qq)
               + (orig >> 3);
  const int mt = wg / 6, nt = wg % 6;
  const int m0 = mt * 256, n0 = nt * 256;

  const int tid = threadIdx.x;
  const int lane = tid & 63;
  const int wid = tid >> 6;
  const int wm = wid >> 2, wn = wid & 3;          // wave tile 128x64
  const int lanel = lane & 15, laneq = lane >> 4;
  const int swz = (lanel & 7) << 4;

  // LDS region offsets: A[buf][half] then B[buf][half], 16KB each
  auto AOFF = [](int b, int h) { return b * 32768 + h * 16384; };
  auto BOFF = [](int b, int h) { return 65536 + b * 32768 + h * 16384; };

  // stage one 16KB half-tile (2 gloads/thread). mat: 0=A, 1=B.
  auto stage = [&](int mat, int tau, int h) {
    const int base = (mat == 0 ? AOFF(tau & 1, h) : BOFF(tau & 1, h));
#pragma unroll
    for (int li = 0; li < 2; ++li) {
      const int P = (li * 512 + tid) * 16;
      const int r128 = P >> 7;
      const int cb = P & 127;
      const int k = tau * 64 + (((cb) ^ ((r128 & 7) << 4)) >> 1);
      if (mat == 0) {
        const int grow = m0 + (r128 >> 6) * 128 + h * 64 + (r128 & 63);
        gload_lds16(&A[(size_t)grow * C_DIM + k], smemb + base + P);
      } else {
        const int gcol = n0 + (r128 >> 5) * 64 + h * 32 + (r128 & 31);
        gload_lds16(&Bw[(size_t)gcol * C_DIM + k], smemb + base + P);
      }
    }
  };

  f32x4 acc[8][4] = {};
  short8 av[4][2], bv0[2][2], bv1[2][2];

  auto read_av = [&](int buf, int qm) {
#pragma unroll
    for (int mi = 0; mi < 4; ++mi)
#pragma unroll
      for (int kk = 0; kk < 2; ++kk) {
        const int r128 = wm * 64 + mi * 16 + lanel;
        av[mi][kk] = *(const short8*)(smemb + AOFF(buf, qm) + r128 * 128 +
                                      ((kk * 64 + laneq * 16) ^ swz));
      }
  };
  auto read_bv = [&](int buf, int qn, short8 (*bv)[2]) {
#pragma unroll
    for (int ni = 0; ni < 2; ++ni)
#pragma unroll
      for (int kk = 0; kk < 2; ++kk) {
        const int c128 = wn * 32 + ni * 16 + lanel;
        bv[ni][kk] = *(const short8*)(smemb + BOFF(buf, qn) + c128 * 128 +
                                      ((kk * 64 + laneq * 16) ^ swz));
      }
  };

#define SB() __builtin_amdgcn_sched_barrier(0)
#define BAR() do { SB(); __builtin_amdgcn_s_barrier(); SB(); } while (0)
#define LGKM0() do { asm volatile("s_waitcnt lgkmcnt(0)" ::: "memory"); SB(); } while (0)
#define MFMA_Q(qm, qn, BV)                                             \
  do {                                                                 \
    __builtin_amdgcn_s_setprio(1);                                     \
    _Pragma("unroll") for (int kk = 0; kk < 2; ++kk)                   \
    _Pragma("unroll") for (int mi = 0; mi < 4; ++mi)                   \
    _Pragma("unroll") for (int ni = 0; ni < 2; ++ni)                   \
      acc[(qm)*4 + mi][(qn)*2 + ni] =                                  \
          __builtin_amdgcn_mfma_f32_16x16x32_bf16(                     \
              av[mi][kk], BV[ni][kk], acc[(qm)*4 + mi][(qn)*2 + ni],   \
              0, 0, 0);                                                \
    __builtin_amdgcn_s_setprio(0);                                     \
  } while (0)

  // prologue: fully stage tiles 0 (buf0) and 1 (buf1): 16 loads/thread
  stage(0, 0, 0); stage(1, 0, 0); stage(1, 0, 1); stage(0, 0, 1);
  stage(0, 1, 0); stage(1, 1, 0); stage(1, 1, 1); stage(0, 1, 1);

#pragma unroll
  for (int it2 = 0; it2 < KT / 2; ++it2) {
    const int T = 2 * it2;
    // ---- P0 (tile T, buf0, Q(0,0)) ----
    if (it2 > 0) stage(0, T + 1, 1);              // Ah1(T+1) -> buf1.Ah1
    asm volatile("s_waitcnt vmcnt(8)" ::: "memory");
    BAR();                                         // tile T fully in LDS
    read_av(0, 0); read_bv(0, 0, bv0);
    LGKM0();
    MFMA_Q(0, 0, bv0);
    BAR();
    // ---- P1 (Q(0,1)) ----
    read_bv(0, 1, bv1);
    if (T + 2 < KT) stage(0, T + 2, 0);           // Ah0(T+2) over buf0.Ah0
    BAR();
    LGKM0();
    MFMA_Q(0, 1, bv1);
    BAR();
    // ---- P2 (Q(1,0)) ----
    read_av(0, 1);
    if (T + 2 < KT) stage(1, T + 2, 0);           // Bh0(T+2)
    BAR();
    LGKM0();
    MFMA_Q(1, 0, bv0);
    BAR();
    // ---- P3 (Q(1,1)) ----
    if (T + 2 < KT) stage(1, T + 2, 1);           // Bh1(T+2)
    BAR();
    MFMA_Q(1, 1, bv1);
    BAR();
    // ---- P4 (tile T+1, buf1, Q(0,0)) ----
    if (T + 2 < KT) stage(0, T + 2, 1);           // Ah1(T+2)
    if (T + 2 < KT)
      asm volatile("s_waitcnt vmcnt(8)" ::: "memory");
    else
      asm volatile("s_waitcnt vmcnt(0)" ::: "memory");
    BAR();                                         // tile T+1 fully in LDS
    read_av(1, 0); read_bv(1, 0, bv0);
    LGKM0();
    MFMA_Q(0, 0, bv0);
    BAR();
    // ---- P5 (Q(0,1)) ----
    read_bv(1, 1, bv1);
    if (T + 3 < KT) stage(0, T + 3, 0);           // Ah0(T+3) over buf1.Ah0
    BAR();
    LGKM0();
    MFMA_Q(0, 1, bv1);
    BAR();
    // ---- P6 (Q(1,0)) ----
    read_av(1, 1);
    if (T + 3 < KT) stage(1, T + 3, 0);           // Bh0(T+3)
    BAR();
    LGKM0();
    MFMA_Q(1, 0, bv0);
    BAR();
    // ---- P7 (Q(1,1)) ----
    if (T + 3 < KT) stage(1, T + 3, 1);           // Bh1(T+3)
    BAR();
    MFMA_Q(1, 1, bv1);
    BAR();
  }

  // ---- epilogue: coef*relu + bf16 via full 128KB swizzled LDS transpose ----
  const unsigned int pm = *presentp;
  __syncthreads();
#pragma unroll
  for (int mi = 0; mi < 8; ++mi) {
    const int r0 = wm * 128 + mi * 16 + laneq * 4;
    const int mg = m0 + r0;
    const float4 t0 = *(const float4*)&topw[mg * 2];
    const float4 t1 = *(const float4*)&topw[mg * 2 + 4];
#pragma unroll
    for (int ni = 0; ni < 4; ++ni) {
      const int cl = wn * 64 + ni * 16 + lanel;
      const int e = (n0 + cl) / HID_DIM;
      const float P0e = (float)((pm >> e) & 1u);
      const float P1e = (float)((pm >> (4 + e)) & 1u);
      const float bvv = bias[n0 + cl];
      const float cj[4] = {P0e * t0.x + P1e * t0.y, P0e * t0.z + P1e * t0.w,
                           P0e * t1.x + P1e * t1.y, P0e * t1.z + P1e * t1.w};
#pragma unroll
      for (int j = 0; j < 4; ++j) {
        const int rr = r0 + j;
        float v = fmaxf(acc[mi][ni][j] + bvv, 0.f);
        *(ushort_t*)(smemb + rr * 512 + ((cl * 2) ^ ((rr & 7) << 4))) =
            f2bf(cj[j] * v);
      }
    }
  }
  __syncthreads();
#pragma unroll
  for (int it = 0; it < 16; ++it) {
    const int c = it * 512 + tid;
    const int row = c >> 5, c8 = c & 31;
    short8 v = *(const short8*)(smemb + row * 512 +
                                ((c8 * 16) ^ ((row & 7) << 4)));
    *(short8*)&hOut[(size_t)(m0 + row) * NH + n0 + c8 * 8] = v;
  }
#undef SB
#undef BAR
#undef LGKM0
#undef MFMA_Q
}

// -------- GEMM2 (r3 proven): 128x128, BK=64, 4 waves, dbuf 64KB -------------
__global__ __launch_bounds__(256, 2) void gemm2_k(
    const ushort_t* __restrict__ A, const ushort_t* __restrict__ Bw,
    const float* __restrict__ bias, const float* __restrict__ topw,
    const unsigned int* __restrict__ presentp, float* __restrict__ outp) {
  constexpr int KDIM = NH, BK = 64;
  constexpr int KT = KDIM / BK;                   // 24
  constexpr int NTN = C_DIM / 128;                // 3
  constexpr int ASZ = 128 * BK;                   // 8192 ushorts = 16 KB
  __shared__ ushort_t smem[4 * ASZ];              // 64 KB

  const int nwg = NTN * (NTOK / 128);
  const int orig = blockIdx.x;
  const int xcd = orig & 7;
  const int qq = nwg >> 3, rr = nwg & 7;
  const int wg = (xcd < rr ? xcd * (qq + 1) : rr * (qq + 1) + (xcd - rr) * qq)
               + (orig >> 3);
  const int mt = wg / NTN, nt = wg % NTN;
  const int m0 = mt * 128, n0 = nt * 128;

  const int tid = threadIdx.x;
  const int lane = tid & 63;
  const int wid = tid >> 6;
  const int wm = wid >> 1, wn = wid & 1;
  const int lanel = lane & 15, laneq = lane >> 4;

  auto stage = [&](int t) {
    ushort_t* dstA = smem + (t & 1) * ASZ;
    ushort_t* dstB = smem + 2 * ASZ + (t & 1) * ASZ;
    const int kb = t * BK;
#pragma unroll
    for (int li = 0; li < 4; ++li) {
      const int P = (li * 256 + tid) * 16;
      const int row = P >> 7;
      const int cb = (P & 127) ^ ((row & 7) << 4);
      gload_lds16(&A[(size_t)(m0 + row) * KDIM + kb + (cb >> 1)],
                  (char*)dstA + P);
    }
#pragma unroll
    for (int li = 0; li < 4; ++li) {
      const int P = (li * 256 + tid) * 16;
      const int row = P >> 7;
      const int cb = (P & 127) ^ ((row & 7) << 4);
      gload_lds16(&Bw[(size_t)(n0 + row) * KDIM + kb + (cb >> 1)],
                  (char*)dstB + P);
    }
  };

  f32x4 acc[4][4] = {};

  stage(0);
  stage(1);
  for (int t = 0; t < KT; ++t) {
    if (t + 1 < KT)
      asm volatile("s_waitcnt vmcnt(8)" ::: "memory");
    else
      asm volatile("s_waitcnt vmcnt(0)" ::: "memory");
    __builtin_amdgcn_sched_barrier(0);
    __builtin_amdgcn_s_barrier();
    __builtin_amdgcn_sched_barrier(0);
    const char* Ab = (const char*)(smem + (t & 1) * ASZ);
    const char* Bb = (const char*)(smem + 2 * ASZ + (t & 1) * ASZ);
    short8 av[4][2], bv[4][2];
#pragma unroll
    for (int i = 0; i < 4; ++i)
#pragma unroll
      for (int kk = 0; kk < 2; ++kk) {
        const int row = wm * 64 + i * 16 + lanel;
        const int cb = (kk * 64 + (laneq * 16)) ^ ((row & 7) << 4);
        av[i][kk] = *(const short8*)(Ab + row * 128 + cb);
      }
#pragma unroll
    for (int i = 0; i < 4; ++i)
#pragma unroll
      for (int kk = 0; kk < 2; ++kk) {
        const int row = wn * 64 + i * 16 + lanel;
        const int cb = (kk * 64 + (laneq * 16)) ^ ((row & 7) << 4);
        bv[i][kk] = *(const short8*)(Bb + row * 128 + cb);
      }
    __builtin_amdgcn_s_setprio(1);
#pragma unroll
    for (int kk = 0; kk < 2; ++kk)
#pragma unroll
      for (int i = 0; i < 4; ++i)
#pragma unroll
        for (int j = 0; j < 4; ++j)
          acc[i][j] = __builtin_amdgcn_mfma_f32_16x16x32_bf16(
              av[i][kk], bv[j][kk], acc[i][j], 0, 0, 0);
    __builtin_amdgcn_s_setprio(0);
    __builtin_amdgcn_sched_barrier(0);
    __builtin_amdgcn_s_barrier();
    __builtin_amdgcn_sched_barrier(0);
    if (t + 2 < KT) stage(t + 2);
  }

  const unsigned int pm = *presentp;
  float B0[4], B1[4];
#pragma unroll
  for (int ni = 0; ni < 4; ++ni) {
    const int o = n0 + wn * 64 + ni * 16 + lanel;
    float s0 = 0.f, s1 = 0.f;
#pragma unroll
    for (int e2 = 0; e2 < 4; ++e2) {
      const float bb = bias[e2 * C_DIM + o];
      s0 += (float)((pm >> e2) & 1u) * bb;
      s1 += (float)((pm >> (4 + e2)) & 1u) * bb;
    }
    B0[ni] = s0; B1[ni] = s1;
  }
#pragma unroll
  for (int mi = 0; mi < 4; ++mi) {
    const int mg = m0 + wm * 64 + mi * 16 + laneq * 4;
    const float4 t0 = *(const float4*)&topw[mg * 2];
    const float4 t1 = *(const float4*)&topw[mg * 2 + 4];
    const int bb2 = mg / HW_DIM;
    const int p = mg - bb2 * HW_DIM;
#pragma unroll
    for (int ni = 0; ni < 4; ++ni) {
      const int o = n0 + wn * 64 + ni * 16 + lanel;
      float4 v;
      v.x = acc[mi][ni][0] + t0.x * B0[ni] + t0.y * B1[ni];
      v.y = acc[mi][ni][1] + t0.z * B0[ni] + t0.w * B1[ni];
      v.z = acc[mi][ni][2] + t1.x * B0[ni] + t1.y * B1[ni];
      v.w = acc[mi][ni][3] + t1.z * B0[ni] + t1.w * B1[ni];
      *(float4*)&outp[((size_t)bb2 * C_DIM + o) * HW_DIM + p] = v;
    }
  }
}

extern "C" void kernel_launch(void* const* d_in, const int* in_sizes, int n_in,
                              void* d_out, int out_size, void* d_ws, size_t ws_size,
                              hipStream_t stream) {
  const float* x  = (const float*)d_in[0];
  const float* gw = (const float*)d_in[1];
  const float* gb = (const float*)d_in[2];
  const float* w1 = (const float*)d_in[3];
  const float* b1 = (const float*)d_in[4];
  const float* w2 = (const float*)d_in[5];
  const float* b2 = (const float*)d_in[6];
  float* out = (float*)d_out;

  char* ws = (char*)d_ws;
  ushort_t* xb = (ushort_t*)ws;   ws += (size_t)NTOK * C_DIM * 2;
  ushort_t* hdnS = (ushort_t*)ws; ws += (size_t)NTOK * NH * 2;
  ushort_t* W1b = (ushort_t*)ws;  ws += (size_t)NH * C_DIM * 2;
  ushort_t* W2b = (ushort_t*)ws;  ws += (size_t)C_DIM * NH * 2;
  float* topw = (float*)ws;       ws += (size_t)NTOK * 2 * 4;
  unsigned int* present = (unsigned int*)ws;

  prep_kernel<<<dim3((NH * C_DIM) / 256), dim3(256), 0, stream>>>(
      w1, w2, W1b, W2b, present);
  gate_kernel<<<dim3(B_DIM, 13), dim3(256), 0, stream>>>(
      x, gw, gb, xb, topw, present);
  moe_g1<<<dim3((NTOK / 256) * (NH / 256)), dim3(512), 0, stream>>>(
      xb, W1b, b1, topw, present, hdnS);
  gemm2_k<<<dim3((NTOK / 128) * (C_DIM / 128)), dim3(256), 0, stream>>>(
      hdnS, W2b, b2, topw, present, out);
}

// Round 11
// 122.235 us; speedup vs baseline: 1.2132x; 1.1351x over previous
//
#include <hip/hip_runtime.h>
#include <hip/hip_bf16.h>
#include <stdint.h>

// ConvMoE: B=32, C=384, H=W=28, E=4, HID=384, K=2. N tokens = 25088.
// GEMM1: [25088,384] x [1536,384]^T -> hdnS (coef*relu fused, bf16)
// GEMM2: [25088,1536] x [384,1536]^T -> out (fp32) + sum_e coef*b2
// Both: 128x128 tile, BK=32, 4 waves, THREE 16KB buffers (48KB -> 3 blk/CU),
// stage issued 2 steps ahead (top of loop), counted vmcnt(8).
// Rationale: r3's per-block rate already matches m97; the 874-vs-540 gap is
// blocks/CU (3 vs 2). This keeps r3's schedule and adds the third block.
#define B_DIM 32
#define C_DIM 384
#define HW_DIM 784
#define E_DIM 4
#define HID_DIM 384
#define NTOK (B_DIM * HW_DIM)   // 25088
#define NH (E_DIM * HID_DIM)    // 1536

using short8 = __attribute__((ext_vector_type(8))) short;
using f32x4  = __attribute__((ext_vector_type(4))) float;
typedef unsigned short ushort_t;

__device__ __forceinline__ ushort_t f2bf(float f) {
  __hip_bfloat16 h = __float2bfloat16(f);
  return __builtin_bit_cast(ushort_t, h);
}

__device__ __forceinline__ void gload_lds16(const void* g, void* l) {
  __builtin_amdgcn_global_load_lds(
      (const __attribute__((address_space(1))) unsigned int*)g,
      (__attribute__((address_space(3))) unsigned int*)l, 16, 0, 0);
}

// ---------------- kernel 1: weight convert (+ zero present mask) -------------
__global__ __launch_bounds__(256) void prep_kernel(
    const float* __restrict__ w1, const float* __restrict__ w2,
    ushort_t* __restrict__ W1b, ushort_t* __restrict__ W2b,
    unsigned int* __restrict__ present) {
  int i = blockIdx.x * 256 + threadIdx.x;
  if (i == 0) *present = 0u;
  if (i < NH * C_DIM) {
    W1b[i] = f2bf(w1[i]);                       // [e*HID+d][c]
    int o = i / NH;
    int r = i - o * NH;
    int e = r / HID_DIM;
    int k = r - e * HID_DIM;
    W2b[i] = f2bf(w2[((size_t)e * C_DIM + o) * HID_DIM + k]);  // [o][e*384+k]
  }
}

// ------- kernel 2: gate + softmax + top2 + x -> bf16 [N][C] (512 thr) --------
__global__ __launch_bounds__(512) void gate_kernel(
    const float* __restrict__ x, const float* __restrict__ gw,
    const float* __restrict__ gb, ushort_t* __restrict__ xb,
    float* __restrict__ topw, unsigned int* __restrict__ present) {
  __shared__ __align__(16) ushort_t lxs[64][392];
  __shared__ float pscore[8][64][4];
  __shared__ unsigned int pmask;
  const int b = blockIdx.x;
  const int p0 = blockIdx.y * 64;
  const int cnt = min(64, HW_DIM - p0);
  const int tid = threadIdx.x;
  const int cg = tid >> 6, tl = tid & 63;     // 8 c-groups x 64 p-lanes
  if (tid == 0) pmask = 0u;
  float a0 = 0.f, a1 = 0.f, a2 = 0.f, a3 = 0.f;
  const bool valid = tl < cnt;
  if (valid) {
    const float* xp = x + (size_t)b * C_DIM * HW_DIM + p0 + tl;
    for (int c = cg; c < C_DIM; c += 8) {     // 48 independent loads/thread
      const float v = xp[(size_t)c * HW_DIM];
      lxs[tl][c] = f2bf(v);
      const float4 g = *(const float4*)&gw[c * 4];
      a0 += v * g.x; a1 += v * g.y; a2 += v * g.z; a3 += v * g.w;
    }
  }
  pscore[cg][tl][0] = a0; pscore[cg][tl][1] = a1;
  pscore[cg][tl][2] = a2; pscore[cg][tl][3] = a3;
  __syncthreads();
  if (cg == 0 && valid) {
    float z[4];
#pragma unroll
    for (int e = 0; e < 4; e++) {
      float s = gb[e];
#pragma unroll
      for (int g8 = 0; g8 < 8; g8++) s += pscore[g8][tl][e];
      z[e] = s;
    }
    const float mx = fmaxf(fmaxf(z[0], z[1]), fmaxf(z[2], z[3]));
    float s[4]; float sum = 0.f;
#pragma unroll
    for (int e = 0; e < 4; e++) { s[e] = __expf(z[e] - mx); sum += s[e]; }
    const float inv = 1.f / sum;
#pragma unroll
    for (int e = 0; e < 4; e++) s[e] *= inv;
    int e0 = 0; float v0 = s[0];
#pragma unroll
    for (int e = 1; e < 4; e++) if (s[e] > v0) { v0 = s[e]; e0 = e; }
    int e1 = -1; float v1 = -1.f;
#pragma unroll
    for (int e = 0; e < 4; e++) if (e != e0 && s[e] > v1) { v1 = s[e]; e1 = e; }
    const float r = __expf(v1 - v0);
    const float w0 = 1.f / (1.f + r);
    const int m = b * HW_DIM + p0 + tl;
    topw[m * 2] = w0;
    topw[m * 2 + 1] = 1.f - w0;
    atomicOr(&pmask, (1u << e0) | (1u << (4 + e1)));
  }
  __syncthreads();
  if (tid == 0) atomicOr(present, pmask);
  const int nchunk = cnt * 48;
  for (int ci = tid; ci < nchunk; ci += 512) {
    const int row = ci / 48, c8 = ci - row * 48;
    short8 v = *(const short8*)&lxs[row][c8 * 8];
    *(short8*)&xb[(size_t)(b * HW_DIM + p0 + row) * C_DIM + c8 * 8] = v;
  }
}

// ---- 128x128, BK=32, 4 waves, 3 buffers (48KB -> 3 blk/CU), 2-step lead -----
// T1 XCD-swizzle, T2 both-sides XOR ((row>>1)&3)<<4 (measured 0 conflicts, r8),
// T5 setprio. C[M,128] = A[M,K]*Bw[cols,K]^T; EPI 0: hdnS, 1: out epilogue.
template <int KDIM, int EPI>
__global__ __launch_bounds__(256, 3) void gemm_3b(
    const ushort_t* __restrict__ A, const ushort_t* __restrict__ Bw,
    const float* __restrict__ bias, const float* __restrict__ topw,
    const unsigned int* __restrict__ presentp,
    ushort_t* __restrict__ hOut, float* __restrict__ outp) {
  constexpr int BM = 128, BN = 128, BK = 32;
  constexpr int KT = KDIM / BK;                    // 12 or 48
  constexpr int NTN = (EPI == 0 ? NH / BN : C_DIM / BN);  // 12 or 3
  constexpr int ASZ = BM * BK;                     // 4096 ushorts = 8 KB
  __shared__ ushort_t smem[6 * ASZ];               // A x3, B x3 = 48 KB

  // T1: bijective XCD swizzle (m204); nt-fastest -> same-mt blocks share XCD
  const int nwg = NTN * (NTOK / BM);
  const int orig = blockIdx.x;
  const int xcd = orig & 7;
  const int qq = nwg >> 3, rr = nwg & 7;
  const int wg = (xcd < rr ? xcd * (qq + 1) : rr * (qq + 1) + (xcd - rr) * qq)
               + (orig >> 3);
  const int mt = wg / NTN, nt = wg % NTN;
  const int m0 = mt * BM, n0 = nt * BN;

  const int tid = threadIdx.x;
  const int lane = tid & 63;
  const int wid = tid >> 6;
  const int wm = wid >> 1, wn = wid & 1;           // wave tile 64x64
  const int lanel = lane & 15, laneq = lane >> 4;

  // T2 swizzle (64B rows): key ((row>>1)&3)<<4. Linear LDS dest for
  // global_load_lds, pre-swizzled GLOBAL source; ds_read applies same XOR.
  auto stage = [&](int t) {
    const int buf = t % 3;
    ushort_t* dstA = smem + buf * ASZ;
    ushort_t* dstB = smem + 3 * ASZ + buf * ASZ;
    const int kb = t * BK;
#pragma unroll
    for (int li = 0; li < 2; ++li) {               // A: 8 KB = 512 x 16B
      const int P = (li * 256 + tid) * 16;
      const int row = P >> 6;
      const int cb = (P & 63) ^ (((row >> 1) & 3) << 4);
      gload_lds16(&A[(size_t)(m0 + row) * KDIM + kb + (cb >> 1)],
                  (char*)dstA + P);
    }
#pragma unroll
    for (int li = 0; li < 2; ++li) {               // B: 8 KB
      const int P = (li * 256 + tid) * 16;
      const int row = P >> 6;
      const int cb = (P & 63) ^ (((row >> 1) & 3) << 4);
      gload_lds16(&Bw[(size_t)(n0 + row) * KDIM + kb + (cb >> 1)],
                  (char*)dstB + P);
    }
  };

  f32x4 acc[4][4] = {};
  // per-lane swizzled byte-col: row = base + i*16 + lanel (base%64==0)
  const int cbr = (laneq * 16) ^ (((lanel >> 1) & 3) << 4);

  stage(0);
  stage(1);
  for (int t = 0; t < KT; ++t) {
    // issue tile t+2 now: its buffer ((t+2)%3) was read at step t-1 and is
    // protected by t-1's end barrier. Gives a full-2-step latency lead.
    if (t + 2 < KT) stage(t + 2);
    // counted vmcnt: require tile t's 4 loads done; allow t+1,t+2 in flight
    if (t + 2 < KT)
      asm volatile("s_waitcnt vmcnt(8)" ::: "memory");
    else if (t + 1 < KT)
      asm volatile("s_waitcnt vmcnt(4)" ::: "memory");
    else
      asm volatile("s_waitcnt vmcnt(0)" ::: "memory");
    __builtin_amdgcn_sched_barrier(0);
    __builtin_amdgcn_s_barrier();
    __builtin_amdgcn_sched_barrier(0);
    const int buf = t % 3;
    const char* Ab = (const char*)(smem + buf * ASZ) + (wm * 64 + lanel) * 64;
    const char* Bb =
        (const char*)(smem + 3 * ASZ + buf * ASZ) + (wn * 64 + lanel) * 64;
    short8 av[4], bv[4];
#pragma unroll
    for (int i = 0; i < 4; ++i) av[i] = *(const short8*)(Ab + i * 1024 + cbr);
#pragma unroll
    for (int j = 0; j < 4; ++j) bv[j] = *(const short8*)(Bb + j * 1024 + cbr);
    __builtin_amdgcn_s_setprio(1);                 // T5
#pragma unroll
    for (int i = 0; i < 4; ++i)
#pragma unroll
      for (int j = 0; j < 4; ++j)
        acc[i][j] = __builtin_amdgcn_mfma_f32_16x16x32_bf16(
            av[i], bv[j], acc[i][j], 0, 0, 0);
    __builtin_amdgcn_s_setprio(0);
    __builtin_amdgcn_sched_barrier(0);
    __builtin_amdgcn_s_barrier();                  // all waves done with buf
    __builtin_amdgcn_sched_barrier(0);
  }

  const unsigned int pm = *presentp;
  if constexpr (EPI == 0) {
    // coef*relu + bf16, LDS transpose (smem reused as 128x128 bf16 = 32 KB)
    __syncthreads();
    ushort_t* tr = smem;
    const int e = n0 / HID_DIM;                    // 128-col tile: one expert
    const float P0 = (float)((pm >> e) & 1u);
    const float P1 = (float)((pm >> (4 + e)) & 1u);
#pragma unroll
    for (int mi = 0; mi < 4; ++mi) {
      const int r0 = wm * 64 + mi * 16 + laneq * 4;
      const int mg = m0 + r0;
      const float4 t0 = *(const float4*)&topw[mg * 2];
      const float4 t1 = *(const float4*)&topw[mg * 2 + 4];
      const float cj[4] = {P0 * t0.x + P1 * t0.y, P0 * t0.z + P1 * t0.w,
                           P0 * t1.x + P1 * t1.y, P0 * t1.z + P1 * t1.w};
#pragma unroll
      for (int ni = 0; ni < 4; ++ni) {
        const int cl = wn * 64 + ni * 16 + lanel;
        const float bvv = bias[n0 + cl];
#pragma unroll
        for (int j = 0; j < 4; ++j) {
          float v = fmaxf(acc[mi][ni][j] + bvv, 0.f);
          tr[(r0 + j) * 128 + cl] = f2bf(cj[j] * v);
        }
      }
    }
    __syncthreads();
#pragma unroll
    for (int it = 0; it < 8; ++it) {
      const int c = it * 256 + tid;
      const int row = c >> 4, cr = c & 15;
      *(short8*)&hOut[(size_t)(m0 + row) * NH + n0 + cr * 8] =
          *(const short8*)&tr[row * 128 + cr * 8];
    }
  } else {
    float B0[4], B1[4];
#pragma unroll
    for (int ni = 0; ni < 4; ++ni) {
      const int o = n0 + wn * 64 + ni * 16 + lanel;
      float s0 = 0.f, s1 = 0.f;
#pragma unroll
      for (int e2 = 0; e2 < 4; ++e2) {
        const float bb = bias[e2 * C_DIM + o];
        s0 += (float)((pm >> e2) & 1u) * bb;
        s1 += (float)((pm >> (4 + e2)) & 1u) * bb;
      }
      B0[ni] = s0; B1[ni] = s1;
    }
#pragma unroll
    for (int mi = 0; mi < 4; ++mi) {
      const int mg = m0 + wm * 64 + mi * 16 + laneq * 4;
      const float4 t0 = *(const float4*)&topw[mg * 2];
      const float4 t1 = *(const float4*)&topw[mg * 2 + 4];
      const int bb2 = mg / HW_DIM;
      const int p = mg - bb2 * HW_DIM;             // 4 consecutive p, same b
#pragma unroll
      for (int ni = 0; ni < 4; ++ni) {
        const int o = n0 + wn * 64 + ni * 16 + lanel;
        float4 v;
        v.x = acc[mi][ni][0] + t0.x * B0[ni] + t0.y * B1[ni];
        v.y = acc[mi][ni][1] + t0.z * B0[ni] + t0.w * B1[ni];
        v.z = acc[mi][ni][2] + t1.x * B0[ni] + t1.y * B1[ni];
        v.w = acc[mi][ni][3] + t1.z * B0[ni] + t1.w * B1[ni];
        *(float4*)&outp[((size_t)bb2 * C_DIM + o) * HW_DIM + p] = v;
      }
    }
  }
}

extern "C" void kernel_launch(void* const* d_in, const int* in_sizes, int n_in,
                              void* d_out, int out_size, void* d_ws, size_t ws_size,
                              hipStream_t stream) {
  const float* x  = (const float*)d_in[0];
  const float* gw = (const float*)d_in[1];
  const float* gb = (const float*)d_in[2];
  const float* w1 = (const float*)d_in[3];
  const float* b1 = (const float*)d_in[4];
  const float* w2 = (const float*)d_in[5];
  const float* b2 = (const float*)d_in[6];
  float* out = (float*)d_out;

  char* ws = (char*)d_ws;
  ushort_t* xb = (ushort_t*)ws;   ws += (size_t)NTOK * C_DIM * 2;
  ushort_t* hdnS = (ushort_t*)ws; ws += (size_t)NTOK * NH * 2;
  ushort_t* W1b = (ushort_t*)ws;  ws += (size_t)NH * C_DIM * 2;
  ushort_t* W2b = (ushort_t*)ws;  ws += (size_t)C_DIM * NH * 2;
  float* topw = (float*)ws;       ws += (size_t)NTOK * 2 * 4;
  unsigned int* present = (unsigned int*)ws;

  prep_kernel<<<dim3((NH * C_DIM) / 256), dim3(256), 0, stream>>>(
      w1, w2, W1b, W2b, present);
  gate_kernel<<<dim3(B_DIM, 13), dim3(512), 0, stream>>>(
      x, gw, gb, xb, topw, present);
  gemm_3b<C_DIM, 0>
      <<<dim3((NTOK / 128) * (NH / 128)), dim3(256), 0, stream>>>(
          xb, W1b, b1, topw, present, hdnS, nullptr);
  gemm_3b<NH, 1>
      <<<dim3((NTOK / 128) * (C_DIM / 128)), dim3(256), 0, stream>>>(
          hdnS, W2b, b2, topw, present, nullptr, out);
}

// Round 12
// 121.748 us; speedup vs baseline: 1.2181x; 1.0040x over previous
//
#include <hip/hip_runtime.h>
#include <hip/hip_bf16.h>
#include <stdint.h>

// ConvMoE: B=32, C=384, H=W=28, E=4, HID=384, K=2. N tokens = 25088.
// GEMM1: [25088,384] x [1536,384]^T -> hdnS (coef*relu fused, bf16)
// GEMM2: [25088,1536] x [384,1536]^T -> out (fp32) + sum_e coef*b2
// Both: 128x128 tile, BK=32, 4 waves, THREE 16KB buffers (48KB -> 3 blk/CU),
// SINGLE barrier per K-step: [vmcnt(4); barrier; stage(t+2); ds_read; MFMA].
// Safety: at step t's barrier every wave has consumed its step t-1 fragments,
// so buffer (t+2)%3 (last read at t-1) is write-safe after the barrier.
#define B_DIM 32
#define C_DIM 384
#define HW_DIM 784
#define E_DIM 4
#define HID_DIM 384
#define NTOK (B_DIM * HW_DIM)   // 25088
#define NH (E_DIM * HID_DIM)    // 1536

using short8 = __attribute__((ext_vector_type(8))) short;
using f32x4  = __attribute__((ext_vector_type(4))) float;
typedef unsigned short ushort_t;

__device__ __forceinline__ ushort_t f2bf(float f) {
  __hip_bfloat16 h = __float2bfloat16(f);
  return __builtin_bit_cast(ushort_t, h);
}

__device__ __forceinline__ void gload_lds16(const void* g, void* l) {
  __builtin_amdgcn_global_load_lds(
      (const __attribute__((address_space(1))) unsigned int*)g,
      (__attribute__((address_space(3))) unsigned int*)l, 16, 0, 0);
}

// ---------------- kernel 1: weight convert (+ zero present mask) -------------
__global__ __launch_bounds__(256) void prep_kernel(
    const float* __restrict__ w1, const float* __restrict__ w2,
    ushort_t* __restrict__ W1b, ushort_t* __restrict__ W2b,
    unsigned int* __restrict__ present) {
  int i = blockIdx.x * 256 + threadIdx.x;
  if (i == 0) *present = 0u;
  if (i < NH * C_DIM) {
    W1b[i] = f2bf(w1[i]);                       // [e*HID+d][c]
    int o = i / NH;
    int r = i - o * NH;
    int e = r / HID_DIM;
    int k = r - e * HID_DIM;
    W2b[i] = f2bf(w2[((size_t)e * C_DIM + o) * HID_DIM + k]);  // [o][e*384+k]
  }
}

// ------- kernel 2: gate + softmax + top2 + x -> bf16 [N][C] (512 thr) --------
__global__ __launch_bounds__(512) void gate_kernel(
    const float* __restrict__ x, const float* __restrict__ gw,
    const float* __restrict__ gb, ushort_t* __restrict__ xb,
    float* __restrict__ topw, unsigned int* __restrict__ present) {
  __shared__ __align__(16) ushort_t lxs[64][392];
  __shared__ float pscore[8][64][4];
  __shared__ unsigned int pmask;
  const int b = blockIdx.x;
  const int p0 = blockIdx.y * 64;
  const int cnt = min(64, HW_DIM - p0);
  const int tid = threadIdx.x;
  const int cg = tid >> 6, tl = tid & 63;     // 8 c-groups x 64 p-lanes
  if (tid == 0) pmask = 0u;
  float a0 = 0.f, a1 = 0.f, a2 = 0.f, a3 = 0.f;
  const bool valid = tl < cnt;
  if (valid) {
    const float* xp = x + (size_t)b * C_DIM * HW_DIM + p0 + tl;
    for (int c = cg; c < C_DIM; c += 8) {
      const float v = xp[(size_t)c * HW_DIM];
      lxs[tl][c] = f2bf(v);
      const float4 g = *(const float4*)&gw[c * 4];
      a0 += v * g.x; a1 += v * g.y; a2 += v * g.z; a3 += v * g.w;
    }
  }
  pscore[cg][tl][0] = a0; pscore[cg][tl][1] = a1;
  pscore[cg][tl][2] = a2; pscore[cg][tl][3] = a3;
  __syncthreads();
  if (cg == 0 && valid) {
    float z[4];
#pragma unroll
    for (int e = 0; e < 4; e++) {
      float s = gb[e];
#pragma unroll
      for (int g8 = 0; g8 < 8; g8++) s += pscore[g8][tl][e];
      z[e] = s;
    }
    const float mx = fmaxf(fmaxf(z[0], z[1]), fmaxf(z[2], z[3]));
    float s[4]; float sum = 0.f;
#pragma unroll
    for (int e = 0; e < 4; e++) { s[e] = __expf(z[e] - mx); sum += s[e]; }
    const float inv = 1.f / sum;
#pragma unroll
    for (int e = 0; e < 4; e++) s[e] *= inv;
    int e0 = 0; float v0 = s[0];
#pragma unroll
    for (int e = 1; e < 4; e++) if (s[e] > v0) { v0 = s[e]; e0 = e; }
    int e1 = -1; float v1 = -1.f;
#pragma unroll
    for (int e = 0; e < 4; e++) if (e != e0 && s[e] > v1) { v1 = s[e]; e1 = e; }
    const float r = __expf(v1 - v0);
    const float w0 = 1.f / (1.f + r);
    const int m = b * HW_DIM + p0 + tl;
    topw[m * 2] = w0;
    topw[m * 2 + 1] = 1.f - w0;
    atomicOr(&pmask, (1u << e0) | (1u << (4 + e1)));
  }
  __syncthreads();
  if (tid == 0) atomicOr(present, pmask);
  const int nchunk = cnt * 48;
  for (int ci = tid; ci < nchunk; ci += 512) {
    const int row = ci / 48, c8 = ci - row * 48;
    short8 v = *(const short8*)&lxs[row][c8 * 8];
    *(short8*)&xb[(size_t)(b * HW_DIM + p0 + row) * C_DIM + c8 * 8] = v;
  }
}

// -- 128x128, BK=32, 4 waves, 3 buffers (48KB, 3 blk/CU), 1 barrier per step --
// T1 XCD-swizzle, T2 both-sides XOR ((row>>1)&3)<<4 (measured 0 conflicts), T5.
// C[M,128] = A[M,K]*Bw[cols,K]^T; EPI 0: hdnS epilogue, 1: out epilogue.
template <int KDIM, int EPI>
__global__ __launch_bounds__(256, 3) void gemm_1b(
    const ushort_t* __restrict__ A, const ushort_t* __restrict__ Bw,
    const float* __restrict__ bias, const float* __restrict__ topw,
    const unsigned int* __restrict__ presentp,
    ushort_t* __restrict__ hOut, float* __restrict__ outp) {
  constexpr int BM = 128, BN = 128, BK = 32;
  constexpr int KT = KDIM / BK;                    // 12 or 48
  constexpr int NTN = (EPI == 0 ? NH / BN : C_DIM / BN);  // 12 or 3
  constexpr int ASZ = BM * BK;                     // 4096 ushorts = 8 KB
  __shared__ ushort_t smem[6 * ASZ];               // A x3, B x3 = 48 KB

  // T1: bijective XCD swizzle (m204); nt-fastest -> same-mt blocks share XCD
  const int nwg = NTN * (NTOK / BM);
  const int orig = blockIdx.x;
  const int xcd = orig & 7;
  const int qq = nwg >> 3, rr = nwg & 7;
  const int wg = (xcd < rr ? xcd * (qq + 1) : rr * (qq + 1) + (xcd - rr) * qq)
               + (orig >> 3);
  const int mt = wg / NTN, nt = wg % NTN;
  const int m0 = mt * BM, n0 = nt * BN;

  const int tid = threadIdx.x;
  const int lane = tid & 63;
  const int wid = tid >> 6;
  const int wm = wid >> 1, wn = wid & 1;           // wave tile 64x64
  const int lanel = lane & 15, laneq = lane >> 4;

  // T2 swizzle (64B rows): key ((row>>1)&3)<<4. Linear LDS dest for
  // global_load_lds, pre-swizzled GLOBAL source; ds_read applies same XOR.
  auto stage = [&](int t) {
    const int buf = t % 3;
    ushort_t* dstA = smem + buf * ASZ;
    ushort_t* dstB = smem + 3 * ASZ + buf * ASZ;
    const int kb = t * BK;
#pragma unroll
    for (int li = 0; li < 2; ++li) {               // A: 8 KB = 512 x 16B
      const int P = (li * 256 + tid) * 16;
      const int row = P >> 6;
      const int cb = (P & 63) ^ (((row >> 1) & 3) << 4);
      gload_lds16(&A[(size_t)(m0 + row) * KDIM + kb + (cb >> 1)],
                  (char*)dstA + P);
    }
#pragma unroll
    for (int li = 0; li < 2; ++li) {               // B: 8 KB
      const int P = (li * 256 + tid) * 16;
      const int row = P >> 6;
      const int cb = (P & 63) ^ (((row >> 1) & 3) << 4);
      gload_lds16(&Bw[(size_t)(n0 + row) * KDIM + kb + (cb >> 1)],
                  (char*)dstB + P);
    }
  };

  f32x4 acc[4][4] = {};
  // per-lane swizzled byte-col: row = base + i*16 + lanel (base%64==0)
  const int cbr = (laneq * 16) ^ (((lanel >> 1) & 3) << 4);

  stage(0);
  stage(1);
  for (int t = 0; t < KT; ++t) {
    // counted vmcnt: outstanding = tile t (4) + tile t+1 (4); need tile t.
    if (t + 1 < KT)
      asm volatile("s_waitcnt vmcnt(4)" ::: "memory");
    else
      asm volatile("s_waitcnt vmcnt(0)" ::: "memory");
    __builtin_amdgcn_sched_barrier(0);
    __builtin_amdgcn_s_barrier();                  // the ONLY barrier per step
    __builtin_amdgcn_sched_barrier(0);
    // buffer (t+2)%3 was last read at step t-1; every wave consumed its
    // fragments before arriving at this barrier -> write-safe now.
    if (t + 2 < KT) stage(t + 2);
    const int buf = t % 3;
    const char* Ab = (const char*)(smem + buf * ASZ) + (wm * 64 + lanel) * 64;
    const char* Bb =
        (const char*)(smem + 3 * ASZ + buf * ASZ) + (wn * 64 + lanel) * 64;
    short8 av[4], bv[4];
#pragma unroll
    for (int i = 0; i < 4; ++i) av[i] = *(const short8*)(Ab + i * 1024 + cbr);
#pragma unroll
    for (int j = 0; j < 4; ++j) bv[j] = *(const short8*)(Bb + j * 1024 + cbr);
    __builtin_amdgcn_s_setprio(1);                 // T5
#pragma unroll
    for (int i = 0; i < 4; ++i)
#pragma unroll
      for (int j = 0; j < 4; ++j)
        acc[i][j] = __builtin_amdgcn_mfma_f32_16x16x32_bf16(
            av[i], bv[j], acc[i][j], 0, 0, 0);
    __builtin_amdgcn_s_setprio(0);
  }

  const unsigned int pm = *presentp;
  if constexpr (EPI == 0) {
    // coef*relu + bf16, LDS transpose (smem reused as 128x128 bf16 = 32 KB)
    __syncthreads();
    ushort_t* tr = smem;
    const int e = n0 / HID_DIM;                    // 128-col tile: one expert
    const float P0 = (float)((pm >> e) & 1u);
    const float P1 = (float)((pm >> (4 + e)) & 1u);
#pragma unroll
    for (int mi = 0; mi < 4; ++mi) {
      const int r0 = wm * 64 + mi * 16 + laneq * 4;
      const int mg = m0 + r0;
      const float4 t0 = *(const float4*)&topw[mg * 2];
      const float4 t1 = *(const float4*)&topw[mg * 2 + 4];
      const float cj[4] = {P0 * t0.x + P1 * t0.y, P0 * t0.z + P1 * t0.w,
                           P0 * t1.x + P1 * t1.y, P0 * t1.z + P1 * t1.w};
#pragma unroll
      for (int ni = 0; ni < 4; ++ni) {
        const int cl = wn * 64 + ni * 16 + lanel;
        const float bvv = bias[n0 + cl];
#pragma unroll
        for (int j = 0; j < 4; ++j) {
          float v = fmaxf(acc[mi][ni][j] + bvv, 0.f);
          tr[(r0 + j) * 128 + cl] = f2bf(cj[j] * v);
        }
      }
    }
    __syncthreads();
#pragma unroll
    for (int it = 0; it < 8; ++it) {
      const int c = it * 256 + tid;
      const int row = c >> 4, cr = c & 15;
      *(short8*)&hOut[(size_t)(m0 + row) * NH + n0 + cr * 8] =
          *(const short8*)&tr[row * 128 + cr * 8];
    }
  } else {
    float B0[4], B1[4];
#pragma unroll
    for (int ni = 0; ni < 4; ++ni) {
      const int o = n0 + wn * 64 + ni * 16 + lanel;
      float s0 = 0.f, s1 = 0.f;
#pragma unroll
      for (int e2 = 0; e2 < 4; ++e2) {
        const float bb = bias[e2 * C_DIM + o];
        s0 += (float)((pm >> e2) & 1u) * bb;
        s1 += (float)((pm >> (4 + e2)) & 1u) * bb;
      }
      B0[ni] = s0; B1[ni] = s1;
    }
#pragma unroll
    for (int mi = 0; mi < 4; ++mi) {
      const int mg = m0 + wm * 64 + mi * 16 + laneq * 4;
      const float4 t0 = *(const float4*)&topw[mg * 2];
      const float4 t1 = *(const float4*)&topw[mg * 2 + 4];
      const int bb2 = mg / HW_DIM;
      const int p = mg - bb2 * HW_DIM;             // 4 consecutive p, same b
#pragma unroll
      for (int ni = 0; ni < 4; ++ni) {
        const int o = n0 + wn * 64 + ni * 16 + lanel;
        float4 v;
        v.x = acc[mi][ni][0] + t0.x * B0[ni] + t0.y * B1[ni];
        v.y = acc[mi][ni][1] + t0.z * B0[ni] + t0.w * B1[ni];
        v.z = acc[mi][ni][2] + t1.x * B0[ni] + t1.y * B1[ni];
        v.w = acc[mi][ni][3] + t1.z * B0[ni] + t1.w * B1[ni];
        *(float4*)&outp[((size_t)bb2 * C_DIM + o) * HW_DIM + p] = v;
      }
    }
  }
}

extern "C" void kernel_launch(void* const* d_in, const int* in_sizes, int n_in,
                              void* d_out, int out_size, void* d_ws, size_t ws_size,
                              hipStream_t stream) {
  const float* x  = (const float*)d_in[0];
  const float* gw = (const float*)d_in[1];
  const float* gb = (const float*)d_in[2];
  const float* w1 = (const float*)d_in[3];
  const float* b1 = (const float*)d_in[4];
  const float* w2 = (const float*)d_in[5];
  const float* b2 = (const float*)d_in[6];
  float* out = (float*)d_out;

  char* ws = (char*)d_ws;
  ushort_t* xb = (ushort_t*)ws;   ws += (size_t)NTOK * C_DIM * 2;
  ushort_t* hdnS = (ushort_t*)ws; ws += (size_t)NTOK * NH * 2;
  ushort_t* W1b = (ushort_t*)ws;  ws += (size_t)NH * C_DIM * 2;
  ushort_t* W2b = (ushort_t*)ws;  ws += (size_t)C_DIM * NH * 2;
  float* topw = (float*)ws;       ws += (size_t)NTOK * 2 * 4;
  unsigned int* present = (unsigned int*)ws;

  prep_kernel<<<dim3((NH * C_DIM) / 256), dim3(256), 0, stream>>>(
      w1, w2, W1b, W2b, present);
  gate_kernel<<<dim3(B_DIM, 13), dim3(512), 0, stream>>>(
      x, gw, gb, xb, topw, present);
  gemm_1b<C_DIM, 0>
      <<<dim3((NTOK / 128) * (NH / 128)), dim3(256), 0, stream>>>(
          xb, W1b, b1, topw, present, hdnS, nullptr);
  gemm_1b<NH, 1>
      <<<dim3((NTOK / 128) * (C_DIM / 128)), dim3(256), 0, stream>>>(
          hdnS, W2b, b2, topw, present, nullptr, out);
}

// Round 13
// 120.127 us; speedup vs baseline: 1.2345x; 1.0135x over previous
//
#include <hip/hip_runtime.h>
#include <hip/hip_bf16.h>
#include <stdint.h>

// ConvMoE: B=32, C=384, H=W=28, E=4, HID=384, K=2. N tokens = 25088.
// GEMM1: [25088,384] x W1 -> hdnS (coef*relu fused, bf16)
// GEMM2: [25088,1536] x W2 -> out (fp32) + sum_e coef*b2
// Both: 128x128 tile, BK=32, 4 waves, A in LDS (3 x 8KB buffers, 3 blk/CU),
// B (weights) read DIRECTLY from L2 into VGPRs as pre-packed per-lane
// fragments (prep kernel), double-buffered 1 step ahead.
// Rationale (r12 post-mortem): the ds_read_b128 pipe was 100% saturated
// (96 reads x 12cyc = 1152 of 1164 cyc/step/CU). Moving B off LDS halves it.
#define B_DIM 32
#define C_DIM 384
#define HW_DIM 784
#define E_DIM 4
#define HID_DIM 384
#define NTOK (B_DIM * HW_DIM)   // 25088
#define NH (E_DIM * HID_DIM)    // 1536
#define WSZ 589824              // NH*C_DIM

using short8 = __attribute__((ext_vector_type(8))) short;
using f32x4  = __attribute__((ext_vector_type(4))) float;
typedef unsigned short ushort_t;

__device__ __forceinline__ ushort_t f2bf(float f) {
  __hip_bfloat16 h = __float2bfloat16(f);
  return __builtin_bit_cast(ushort_t, h);
}

__device__ __forceinline__ void gload_lds16(const void* g, void* l) {
  __builtin_amdgcn_global_load_lds(
      (const __attribute__((address_space(1))) unsigned int*)g,
      (__attribute__((address_space(3))) unsigned int*)l, 16, 0, 0);
}

// ---- kernel 1: pack weights into per-lane MFMA fragment order ---------------
// Chunk per (nt,ks): [wn(2)][ni(4)][lane(64)][t(8)] = 4096 elems = 8KB.
// Fragment: B-col = nt*128 + wn*64 + ni*16 + (lane&15), k = ks*32+(lane>>4)*8+t.
__global__ __launch_bounds__(256) void prep_kernel(
    const float* __restrict__ w1, const float* __restrict__ w2,
    ushort_t* __restrict__ W1f, ushort_t* __restrict__ W2f,
    unsigned int* __restrict__ present) {
  int i = blockIdx.x * 256 + threadIdx.x;
  if (i == 0) *present = 0u;
  if (i >= WSZ) return;
  {
    // W1f: nt(12) ks(12) chunk
    int r = i;
    const int nt = r / 49152; r -= nt * 49152;
    const int ks = r / 4096;  r -= ks * 4096;
    const int wn = r >> 11;
    const int ni = (r >> 9) & 3;
    const int ln = (r >> 3) & 63;
    const int tt = r & 7;
    const int row = nt * 128 + wn * 64 + ni * 16 + (ln & 15);
    const int c = ks * 32 + (ln >> 4) * 8 + tt;
    W1f[i] = f2bf(w1[(size_t)row * C_DIM + c]);     // w1 flat [e*HID+d][c]
  }
  {
    // W2f: nt(3) ks(48) chunk
    int r = i;
    const int nt = r / 196608; r -= nt * 196608;
    const int ks = r / 4096;   r -= ks * 4096;
    const int wn = r >> 11;
    const int ni = (r >> 9) & 3;
    const int ln = (r >> 3) & 63;
    const int tt = r & 7;
    const int o = nt * 128 + wn * 64 + ni * 16 + (ln & 15);
    const int kg = ks * 32 + (ln >> 4) * 8 + tt;
    const int e = kg / HID_DIM, d = kg - e * HID_DIM;
    W2f[i] = f2bf(w2[((size_t)e * C_DIM + o) * HID_DIM + d]);  // w2 [E][C][HID]
  }
}

// ------- kernel 2: gate + softmax + top2 + x -> bf16 [N][C] (512 thr) --------
__global__ __launch_bounds__(512) void gate_kernel(
    const float* __restrict__ x, const float* __restrict__ gw,
    const float* __restrict__ gb, ushort_t* __restrict__ xb,
    float* __restrict__ topw, unsigned int* __restrict__ present) {
  __shared__ __align__(16) ushort_t lxs[64][392];
  __shared__ float pscore[8][64][4];
  __shared__ unsigned int pmask;
  const int b = blockIdx.x;
  const int p0 = blockIdx.y * 64;
  const int cnt = min(64, HW_DIM - p0);
  const int tid = threadIdx.x;
  const int cg = tid >> 6, tl = tid & 63;
  if (tid == 0) pmask = 0u;
  float a0 = 0.f, a1 = 0.f, a2 = 0.f, a3 = 0.f;
  const bool valid = tl < cnt;
  if (valid) {
    const float* xp = x + (size_t)b * C_DIM * HW_DIM + p0 + tl;
    for (int c = cg; c < C_DIM; c += 8) {
      const float v = xp[(size_t)c * HW_DIM];
      lxs[tl][c] = f2bf(v);
      const float4 g = *(const float4*)&gw[c * 4];
      a0 += v * g.x; a1 += v * g.y; a2 += v * g.z; a3 += v * g.w;
    }
  }
  pscore[cg][tl][0] = a0; pscore[cg][tl][1] = a1;
  pscore[cg][tl][2] = a2; pscore[cg][tl][3] = a3;
  __syncthreads();
  if (cg == 0 && valid) {
    float z[4];
#pragma unroll
    for (int e = 0; e < 4; e++) {
      float s = gb[e];
#pragma unroll
      for (int g8 = 0; g8 < 8; g8++) s += pscore[g8][tl][e];
      z[e] = s;
    }
    const float mx = fmaxf(fmaxf(z[0], z[1]), fmaxf(z[2], z[3]));
    float s[4]; float sum = 0.f;
#pragma unroll
    for (int e = 0; e < 4; e++) { s[e] = __expf(z[e] - mx); sum += s[e]; }
    const float inv = 1.f / sum;
#pragma unroll
    for (int e = 0; e < 4; e++) s[e] *= inv;
    int e0 = 0; float v0 = s[0];
#pragma unroll
    for (int e = 1; e < 4; e++) if (s[e] > v0) { v0 = s[e]; e0 = e; }
    int e1 = -1; float v1 = -1.f;
#pragma unroll
    for (int e = 0; e < 4; e++) if (e != e0 && s[e] > v1) { v1 = s[e]; e1 = e; }
    const float r = __expf(v1 - v0);
    const float w0 = 1.f / (1.f + r);
    const int m = b * HW_DIM + p0 + tl;
    topw[m * 2] = w0;
    topw[m * 2 + 1] = 1.f - w0;
    atomicOr(&pmask, (1u << e0) | (1u << (4 + e1)));
  }
  __syncthreads();
  if (tid == 0) atomicOr(present, pmask);
  const int nchunk = cnt * 48;
  for (int ci = tid; ci < nchunk; ci += 512) {
    const int row = ci / 48, c8 = ci - row * 48;
    short8 v = *(const short8*)&lxs[row][c8 * 8];
    *(short8*)&xb[(size_t)(b * HW_DIM + p0 + row) * C_DIM + c8 * 8] = v;
  }
}

// -- 128x128, BK=32, 4 waves, A: 3 LDS buffers (24KB); B: direct L2->VGPR -----
// T1 XCD-swizzle, T2 A-swizzle ((row>>1)&3)<<4 (0 conflicts), T5 setprio.
// Per step: [vmcnt(2); barrier; loadB(t+1)->regs; stage A(t+2); dsread; MFMA].
// Issue order per step = B(t+1)x4 then A(t+2)x2 -> wait vmcnt(2) at top
// guarantees A(t) and B(t) complete while A(t+1) stays in flight.
template <int KDIM, int EPI>
__global__ __launch_bounds__(256, 3) void gemm_bg(
    const ushort_t* __restrict__ A, const ushort_t* __restrict__ Wf,
    const float* __restrict__ bias, const float* __restrict__ topw,
    const unsigned int* __restrict__ presentp,
    ushort_t* __restrict__ hOut, float* __restrict__ outp) {
  constexpr int BM = 128, BN = 128, BK = 32;
  constexpr int KT = KDIM / BK;                    // 12 or 48
  constexpr int NTN = (EPI == 0 ? NH / BN : C_DIM / BN);  // 12 or 3
  constexpr int ASZ = BM * BK;                     // 4096 ushorts = 8 KB
  __shared__ ushort_t smem[3 * ASZ];               // 24 KB -> 3 blk/CU (VGPR)

  // T1: bijective XCD swizzle (m204)
  const int nwg = NTN * (NTOK / BM);
  const int orig = blockIdx.x;
  const int xcd = orig & 7;
  const int qq = nwg >> 3, rr = nwg & 7;
  const int wg = (xcd < rr ? xcd * (qq + 1) : rr * (qq + 1) + (xcd - rr) * qq)
               + (orig >> 3);
  const int mt = wg / NTN, nt = wg % NTN;
  const int m0 = mt * BM, n0 = nt * BN;

  const int tid = threadIdx.x;
  const int lane = tid & 63;
  const int wid = tid >> 6;
  const int wm = wid >> 1, wn = wid & 1;           // wave tile 64x64
  const int lanel = lane & 15, laneq = lane >> 4;

  // per-wave fragment base in packed weights: chunk(nt,ks) = 4096 elems
  const ushort_t* wbase = Wf + (size_t)nt * KT * 4096 + wn * 2048 + lane * 8;

  auto stage = [&](int t) {                        // A only: 8KB/step
    ushort_t* dstA = smem + (t % 3) * ASZ;
    const int kb = t * BK;
#pragma unroll
    for (int li = 0; li < 2; ++li) {
      const int P = (li * 256 + tid) * 16;
      const int row = P >> 6;
      const int cb = (P & 63) ^ (((row >> 1) & 3) << 4);
      gload_lds16(&A[(size_t)(m0 + row) * KDIM + kb + (cb >> 1)],
                  (char*)dstA + P);
    }
  };

  auto loadB = [&](int t, short8* bv) {            // 4 frags -> VGPRs
    const ushort_t* p = wbase + (size_t)t * 4096;
    asm volatile(
        "global_load_dwordx4 %0, %4, off\n\t"
        "global_load_dwordx4 %1, %4, off offset:1024\n\t"
        "global_load_dwordx4 %2, %4, off offset:2048\n\t"
        "global_load_dwordx4 %3, %4, off offset:3072"
        : "=&v"(bv[0]), "=&v"(bv[1]), "=&v"(bv[2]), "=&v"(bv[3])
        : "v"(p)
        : "memory");
  };

  f32x4 acc[4][4] = {};
  const int cbr = (laneq * 16) ^ (((lanel >> 1) & 3) << 4);  // A ds_read col

  short8 bvA[4], bvB[4];

  auto step = [&](int t, short8* cur, short8* nxt) {
    if (t + 1 < KT)
      asm volatile("s_waitcnt vmcnt(2)" ::: "memory");
    else
      asm volatile("s_waitcnt vmcnt(0)" ::: "memory");
    __builtin_amdgcn_sched_barrier(0);
    __builtin_amdgcn_s_barrier();                  // one barrier per step
    __builtin_amdgcn_sched_barrier(0);
    if (t + 1 < KT) loadB(t + 1, nxt);             // B first (vmcnt order)
    __builtin_amdgcn_sched_barrier(0);
    if (t + 2 < KT) stage(t + 2);                  // then A
    const char* Ab =
        (const char*)(smem + (t % 3) * ASZ) + (wm * 64 + lanel) * 64;
    short8 av[4];
#pragma unroll
    for (int i = 0; i < 4; ++i) av[i] = *(const short8*)(Ab + i * 1024 + cbr);
    __builtin_amdgcn_s_setprio(1);                 // T5
#pragma unroll
    for (int i = 0; i < 4; ++i)
#pragma unroll
      for (int j = 0; j < 4; ++j)
        acc[i][j] = __builtin_amdgcn_mfma_f32_16x16x32_bf16(
            av[i], cur[j], acc[i][j], 0, 0, 0);
    __builtin_amdgcn_s_setprio(0);
  };

  // prologue order: A(0), B(0), A(1) -> vmcnt(2) at t=0 drains A(0)+B(0)
  stage(0);
  loadB(0, bvA);
  stage(1);
  for (int t = 0; t < KT; t += 2) {                // KT even (12 / 48)
    step(t, bvA, bvB);
    step(t + 1, bvB, bvA);
  }

  const unsigned int pm = *presentp;
  if constexpr (EPI == 0) {
    // coef*relu + bf16, LDS transpose in two 64-row halves (24 KB smem)
    __syncthreads();
    ushort_t* tr = smem;                           // 64x128 bf16 = 16 KB
    const int e = n0 / HID_DIM;                    // 128-col tile: one expert
    const float P0 = (float)((pm >> e) & 1u);
    const float P1 = (float)((pm >> (4 + e)) & 1u);
#pragma unroll
    for (int s = 0; s < 2; ++s) {
      if (wm == s) {
#pragma unroll
        for (int mi = 0; mi < 4; ++mi) {
          const int r0 = mi * 16 + laneq * 4;
          const int mg = m0 + s * 64 + r0;
          const float4 t0 = *(const float4*)&topw[mg * 2];
          const float4 t1 = *(const float4*)&topw[mg * 2 + 4];
          const float cj[4] = {P0 * t0.x + P1 * t0.y, P0 * t0.z + P1 * t0.w,
                               P0 * t1.x + P1 * t1.y, P0 * t1.z + P1 * t1.w};
#pragma unroll
          for (int ni = 0; ni < 4; ++ni) {
            const int cl = wn * 64 + ni * 16 + lanel;
            const float bvv = bias[n0 + cl];
#pragma unroll
            for (int j = 0; j < 4; ++j) {
              float v = fmaxf(acc[mi][ni][j] + bvv, 0.f);
              tr[(r0 + j) * 128 + cl] = f2bf(cj[j] * v);
            }
          }
        }
      }
      __syncthreads();
#pragma unroll
      for (int it = 0; it < 4; ++it) {             // 64x128 = 1024 short8
        const int c = it * 256 + tid;
        const int row = c >> 4, cr = c & 15;
        *(short8*)&hOut[(size_t)(m0 + s * 64 + row) * NH + n0 + cr * 8] =
            *(const short8*)&tr[row * 128 + cr * 8];
      }
      __syncthreads();
    }
  } else {
    float B0[4], B1[4];
#pragma unroll
    for (int ni = 0; ni < 4; ++ni) {
      const int o = n0 + wn * 64 + ni * 16 + lanel;
      float s0 = 0.f, s1 = 0.f;
#pragma unroll
      for (int e2 = 0; e2 < 4; ++e2) {
        const float bb = bias[e2 * C_DIM + o];
        s0 += (float)((pm >> e2) & 1u) * bb;
        s1 += (float)((pm >> (4 + e2)) & 1u) * bb;
      }
      B0[ni] = s0; B1[ni] = s1;
    }
#pragma unroll
    for (int mi = 0; mi < 4; ++mi) {
      const int mg = m0 + wm * 64 + mi * 16 + laneq * 4;
      const float4 t0 = *(const float4*)&topw[mg * 2];
      const float4 t1 = *(const float4*)&topw[mg * 2 + 4];
      const int bb2 = mg / HW_DIM;
      const int p = mg - bb2 * HW_DIM;             // 4 consecutive p, same b
#pragma unroll
      for (int ni = 0; ni < 4; ++ni) {
        const int o = n0 + wn * 64 + ni * 16 + lanel;
        float4 v;
        v.x = acc[mi][ni][0] + t0.x * B0[ni] + t0.y * B1[ni];
        v.y = acc[mi][ni][1] + t0.z * B0[ni] + t0.w * B1[ni];
        v.z = acc[mi][ni][2] + t1.x * B0[ni] + t1.y * B1[ni];
        v.w = acc[mi][ni][3] + t1.z * B0[ni] + t1.w * B1[ni];
        *(float4*)&outp[((size_t)bb2 * C_DIM + o) * HW_DIM + p] = v;
      }
    }
  }
}

extern "C" void kernel_launch(void* const* d_in, const int* in_sizes, int n_in,
                              void* d_out, int out_size, void* d_ws, size_t ws_size,
                              hipStream_t stream) {
  const float* x  = (const float*)d_in[0];
  const float* gw = (const float*)d_in[1];
  const float* gb = (const float*)d_in[2];
  const float* w1 = (const float*)d_in[3];
  const float* b1 = (const float*)d_in[4];
  const float* w2 = (const float*)d_in[5];
  const float* b2 = (const float*)d_in[6];
  float* out = (float*)d_out;

  char* ws = (char*)d_ws;
  ushort_t* xb = (ushort_t*)ws;   ws += (size_t)NTOK * C_DIM * 2;
  ushort_t* hdnS = (ushort_t*)ws; ws += (size_t)NTOK * NH * 2;
  ushort_t* W1f = (ushort_t*)ws;  ws += (size_t)WSZ * 2;
  ushort_t* W2f = (ushort_t*)ws;  ws += (size_t)WSZ * 2;
  float* topw = (float*)ws;       ws += (size_t)NTOK * 2 * 4;
  unsigned int* present = (unsigned int*)ws;

  prep_kernel<<<dim3(WSZ / 256), dim3(256), 0, stream>>>(
      w1, w2, W1f, W2f, present);
  gate_kernel<<<dim3(B_DIM, 13), dim3(512), 0, stream>>>(
      x, gw, gb, xb, topw, present);
  gemm_bg<C_DIM, 0>
      <<<dim3((NTOK / 128) * (NH / 128)), dim3(256), 0, stream>>>(
          xb, W1f, b1, topw, present, hdnS, nullptr);
  gemm_bg<NH, 1>
      <<<dim3((NTOK / 128) * (C_DIM / 128)), dim3(256), 0, stream>>>(
          hdnS, W2f, b2, topw, present, nullptr, out);
}